// Round 5
// baseline (83.933 us; speedup 1.0000x reference)
//
#include <hip/hip_runtime.h>
#include <hip/hip_bf16.h>

#define NB 32
#define NC 128
#define NW 128
#define NH 128
#define BCH (NB * NC * NH)

// One 128-thread (2-wave) block per (b,c) channel -> 8192 waves = 32 waves/CU
// (double R4's occupancy; the kernel is latency-bound, occupancy is the knob).
// Wave wv covers w in [64*wv, 64*wv+64); within a wave, half-wave s covers a
// 32-w window. Lane ll = tid&31 covers h in {ll, ll+32, ll+64, ll+96}.
// Cross-wave combines via LDS: mn BEFORE pass B (both waves must use the same
// shift), partial sums after pass B. Epilogue: thread t finalizes h=t ->
// fully coalesced output stores.
//
// Math (base 2): tile[w] = (sA2, sA2*d, m, m*x), sA2 = sqrt(softplus(k)*log2e)
//   t'  = fma(-sA2, rh, sA2*d)        => t'^2 = A2*(d-rh)^2
//   mn  = (min_w |t'|)^2              (global over all 128 w)
//   v   = fma(-t', t', mn)  <= 0      -> exp2 never overflows
//   e1  = m * exp2(v)                 (shift M = -mn >= max_w s2)
//   e2  = m * exp2(10v) = m * g1^10   (kappa=10 path, 4 muls)
// Peak kappa term has g1=1 at the argmin w -> no 0/0. Shift cancels in
// y, y_t;  w_out = (log2(sum1) - mn) * ln2.
__global__ __launch_bounds__(128, 8) void sci_kernel(
    const void* __restrict__ xp, const void* __restrict__ dp,
    const void* __restrict__ mp, const void* __restrict__ kp,
    void* __restrict__ outp)
{
    const int bc   = blockIdx.x;    // channel 0 .. B*C-1
    const int tid  = threadIdx.x;   // 0 .. 127
    const int wv   = tid >> 6;      // wave id: 0,1
    const int ll   = tid & 31;
    const int wbase = (wv << 6) + ((tid >> 5) & 1) * 32;  // 32-w window start

    __shared__ float4 tile[NW];        // (sA2, sA2*d, m, m*x)
    __shared__ float  mnbuf[2][NH];    // per-wave min|t'| per h
    __shared__ float4 pbuf[2][NH];     // per-wave (s1,a1,s2,a2) per h

    // ---- dtype detection (wave-uniform, deterministic) ----
    const unsigned short* du16 = (const unsigned short*)dp;
    bool is_bf16 = true;
    #pragma unroll
    for (int i = 0; i < 64; i += 2) {
        float v = __uint_as_float(((unsigned int)du16[i]) << 16);
        is_bf16 = is_bf16 && (v >= 0.0f) && (v <= 129.0f);
    }

    // ---- stage this channel into LDS (1 w per thread) ----
    const float LOG2E = 1.4426950408889634f;
    {
        const int base = bc * NW + tid;
        float dv, mv, xv, kv;
        if (is_bf16) {
            dv = __bfloat162float(((const __hip_bfloat16*)dp)[base]);
            mv = __bfloat162float(((const __hip_bfloat16*)mp)[base]);
            xv = __bfloat162float(((const __hip_bfloat16*)xp)[base]);
            kv = __bfloat162float(((const __hip_bfloat16*)kp)[tid]);
        } else {
            dv = ((const float*)dp)[base];
            mv = ((const float*)mp)[base];
            xv = ((const float*)xp)[base];
            kv = ((const float*)kp)[tid];
        }
        float A2  = log1pf(__expf(kv)) * LOG2E;   // softplus(kernel)*log2e
        float sA2 = sqrtf(A2);
        tile[tid] = make_float4(sA2, sA2 * dv, mv, mv * xv);
    }
    __syncthreads();

    // ref_t = linspace(0, H, H) -> step H/(H-1)
    float rh[4];
    #pragma unroll
    for (int j = 0; j < 4; ++j) rh[j] = (float)(ll + 32 * j) * (128.0f / 127.0f);

    // ---- pass A: min|t'| over this half-wave's 32 w ----
    float mna[4] = {3.0e38f, 3.0e38f, 3.0e38f, 3.0e38f};
    #pragma unroll 8
    for (int i = 0; i < 32; ++i) {
        float2 q = *(const float2*)&tile[wbase + i];
        #pragma unroll
        for (int j = 0; j < 4; ++j) {
            float t = __builtin_fmaf(-q.x, rh[j], q.y);
            mna[j] = fminf(mna[j], fabsf(t));   // abs = free input modifier
        }
    }
    // combine half-waves, publish per-wave mins, combine across waves
    #pragma unroll
    for (int j = 0; j < 4; ++j) mna[j] = fminf(mna[j], __shfl_xor(mna[j], 32));
    if ((tid & 63) < 32) {
        #pragma unroll
        for (int j = 0; j < 4; ++j) mnbuf[wv][ll + 32 * j] = mna[j];
    }
    __syncthreads();
    float mn[4];
    #pragma unroll
    for (int j = 0; j < 4; ++j) {
        float a = fminf(mnbuf[0][ll + 32 * j], mnbuf[1][ll + 32 * j]);
        mn[j] = a * a;
    }

    // ---- pass B: partial softmax sums over this half-wave's 32 w ----
    float s1[4] = {0.f, 0.f, 0.f, 0.f}, a1[4] = {0.f, 0.f, 0.f, 0.f};
    float s2[4] = {0.f, 0.f, 0.f, 0.f}, a2[4] = {0.f, 0.f, 0.f, 0.f};
    #pragma unroll 4
    for (int i = 0; i < 32; ++i) {
        float4 q = tile[wbase + i];
        #pragma unroll
        for (int j = 0; j < 4; ++j) {
            float t  = __builtin_fmaf(-q.x, rh[j], q.y);
            float v  = __builtin_fmaf(-t, t, mn[j]);
            float g1 = __builtin_amdgcn_exp2f(v);
            float sq = g1 * g1;
            float p4 = sq * sq;
            float p8 = p4 * p4;
            float g2 = p8 * sq;                 // g1^10 == exp2(10v)
            s1[j] = __builtin_fmaf(q.z, g1, s1[j]);
            a1[j] = __builtin_fmaf(q.w, g1, a1[j]);
            s2[j] = __builtin_fmaf(q.z, g2, s2[j]);
            a2[j] = __builtin_fmaf(q.w, g2, a2[j]);
        }
    }

    // combine half-waves, publish per-wave partials
    #pragma unroll
    for (int j = 0; j < 4; ++j) {
        s1[j] += __shfl_xor(s1[j], 32);
        a1[j] += __shfl_xor(a1[j], 32);
        s2[j] += __shfl_xor(s2[j], 32);
        a2[j] += __shfl_xor(a2[j], 32);
    }
    if ((tid & 63) < 32) {
        #pragma unroll
        for (int j = 0; j < 4; ++j)
            pbuf[wv][ll + 32 * j] = make_float4(s1[j], a1[j], s2[j], a2[j]);
    }
    __syncthreads();

    // ---- epilogue: thread t finalizes h = t (coalesced stores) ----
    {
        float4 P0 = pbuf[0][tid];
        float4 P1 = pbuf[1][tid];
        float S1 = P0.x + P1.x, A1 = P0.y + P1.y;
        float S2 = P0.z + P1.z, A2 = P0.w + P1.w;
        float a  = fminf(mnbuf[0][tid], mnbuf[1][tid]);
        float mnh = a * a;

        const float LN2 = 0.6931471805599453f;
        float y  = A1 * __builtin_amdgcn_rcpf(S1);
        float wvo = (__builtin_amdgcn_logf(S1) - mnh) * LN2;
        float yt = A2 * __builtin_amdgcn_rcpf(S2);

        const int o = bc * NH + tid;
        if (is_bf16) {
            __hip_bfloat16* o16 = (__hip_bfloat16*)outp;
            o16[o]           = __float2bfloat16(y);
            o16[BCH + o]     = __float2bfloat16(wvo);
            o16[2 * BCH + o] = __float2bfloat16(yt);
        } else {
            float* o32 = (float*)outp;
            o32[o]           = y;
            o32[BCH + o]     = wvo;
            o32[2 * BCH + o] = yt;
        }
    }
}

extern "C" void kernel_launch(void* const* d_in, const int* in_sizes, int n_in,
                              void* d_out, int out_size, void* d_ws, size_t ws_size,
                              hipStream_t stream) {
    const void* x_t = d_in[0];
    const void* d   = d_in[1];
    const void* m   = d_in[2];
    const void* k   = d_in[3];
    dim3 grid(NB * NC);
    dim3 block(128);
    hipLaunchKernelGGL(sci_kernel, grid, block, 0, stream, x_t, d, m, k, d_out);
}

// Round 6
// 81.746 us; speedup vs baseline: 1.0268x; 1.0268x over previous
//
#include <hip/hip_runtime.h>
#include <hip/hip_bf16.h>

#define NB 32
#define NC 128
#define NW 128
#define NH 128
#define BCH (NB * NC * NH)

// One 128-thread (2-wave) block per (b,c) channel (R5 layout), plus
// band-sparsity skips: a weight term matters only when |t'| < sqrt(mn+30)
// (g1 > 2^-30); the kappa=10 path only when |t'| < sqrt(mn+3). Both tests
// are wave-uniform votes -> s_cbranch skips the exp2 body ~44% of the time
// and the kappa tail ~50% of the remainder. Skipped e1 terms sum to
// < 128*2^-30 (rel err < 1.2e-4 vs S1 >= 1e-3); skipped g2 terms < 2^-300.
// The argmin-w lane always passes both tests (|t'| = sqrt(mn)), so the
// kappa peak term g2 = 1 is preserved (no 0/0).
//
// Math (base 2): tile[w] = (sA2, sA2*d, m, m*x), sA2 = sqrt(softplus(k)*log2e)
//   t'  = fma(-sA2, rh, sA2*d)        => t'^2 = A2*(d-rh)^2
//   mn  = (min_w |t'|)^2              (global over all 128 w, exact)
//   v   = fma(-t', t', mn)  <= 0      -> exp2 never overflows
//   e1  = m * exp2(v);  e2 = m * exp2(10v) = m * g1^10 (4 muls)
//   w_out = (log2(sum1) - mn) * ln2
__global__ __launch_bounds__(128, 8) void sci_kernel(
    const void* __restrict__ xp, const void* __restrict__ dp,
    const void* __restrict__ mp, const void* __restrict__ kp,
    void* __restrict__ outp)
{
    const int bc   = blockIdx.x;    // channel 0 .. B*C-1
    const int tid  = threadIdx.x;   // 0 .. 127
    const int wv   = tid >> 6;      // wave id: 0,1
    const int ll   = tid & 31;
    const int wbase = (wv << 6) + ((tid >> 5) & 1) * 32;  // 32-w window start

    __shared__ float4 tile[NW];        // (sA2, sA2*d, m, m*x)
    __shared__ float  mnbuf[2][NH];    // per-wave min|t'| per h
    __shared__ float4 pbuf[2][NH];     // per-wave (s1,a1,s2,a2) per h

    // ---- dtype detection (wave-uniform, deterministic) ----
    const unsigned short* du16 = (const unsigned short*)dp;
    bool is_bf16 = true;
    #pragma unroll
    for (int i = 0; i < 32; i += 2) {
        float v = __uint_as_float(((unsigned int)du16[i]) << 16);
        is_bf16 = is_bf16 && (v >= 0.0f) && (v <= 129.0f);
    }

    // ---- stage this channel into LDS (1 w per thread) ----
    const float LOG2E = 1.4426950408889634f;
    {
        const int base = bc * NW + tid;
        float dv, mv, xv, kv;
        if (is_bf16) {
            dv = __bfloat162float(((const __hip_bfloat16*)dp)[base]);
            mv = __bfloat162float(((const __hip_bfloat16*)mp)[base]);
            xv = __bfloat162float(((const __hip_bfloat16*)xp)[base]);
            kv = __bfloat162float(((const __hip_bfloat16*)kp)[tid]);
        } else {
            dv = ((const float*)dp)[base];
            mv = ((const float*)mp)[base];
            xv = ((const float*)xp)[base];
            kv = ((const float*)kp)[tid];
        }
        float A2  = log1pf(__expf(kv)) * LOG2E;   // softplus(kernel)*log2e
        float sA2 = sqrtf(A2);
        tile[tid] = make_float4(sA2, sA2 * dv, mv, mv * xv);
    }
    __syncthreads();

    // ref_t = linspace(0, H, H) -> step H/(H-1)
    float rh[4];
    #pragma unroll
    for (int j = 0; j < 4; ++j) rh[j] = (float)(ll + 32 * j) * (128.0f / 127.0f);

    // ---- pass A: min|t'| over this half-wave's 32 w ----
    float mna[4] = {3.0e38f, 3.0e38f, 3.0e38f, 3.0e38f};
    #pragma unroll 8
    for (int i = 0; i < 32; ++i) {
        float2 q = *(const float2*)&tile[wbase + i];
        #pragma unroll
        for (int j = 0; j < 4; ++j) {
            float t = __builtin_fmaf(-q.x, rh[j], q.y);
            mna[j] = fminf(mna[j], fabsf(t));   // abs = free input modifier
        }
    }
    // combine half-waves, publish per-wave mins, combine across waves
    #pragma unroll
    for (int j = 0; j < 4; ++j) mna[j] = fminf(mna[j], __shfl_xor(mna[j], 32));
    if ((tid & 63) < 32) {
        #pragma unroll
        for (int j = 0; j < 4; ++j) mnbuf[wv][ll + 32 * j] = mna[j];
    }
    __syncthreads();
    float mn[4], Rt[4], Rk[4];
    #pragma unroll
    for (int j = 0; j < 4; ++j) {
        float a = fminf(mnbuf[0][ll + 32 * j], mnbuf[1][ll + 32 * j]);
        mn[j] = a * a;
        Rt[j] = sqrtf(mn[j] + 30.0f);   // |t| beyond this: g1 < 2^-30
        Rk[j] = sqrtf(mn[j] + 3.0f);    // |t| beyond this: g2 < 2^-30
    }

    // ---- pass B: partial softmax sums over this half-wave's 32 w ----
    float s1[4] = {0.f, 0.f, 0.f, 0.f}, a1[4] = {0.f, 0.f, 0.f, 0.f};
    float s2[4] = {0.f, 0.f, 0.f, 0.f}, a2[4] = {0.f, 0.f, 0.f, 0.f};
    #pragma unroll 2
    for (int i = 0; i < 32; ++i) {
        float4 q = tile[wbase + i];
        #pragma unroll
        for (int j = 0; j < 4; ++j) {
            float t = __builtin_fmaf(-q.x, rh[j], q.y);
            if (__any(fabsf(t) < Rt[j])) {
                float v  = __builtin_fmaf(-t, t, mn[j]);
                float g1 = __builtin_amdgcn_exp2f(v);
                s1[j] = __builtin_fmaf(q.z, g1, s1[j]);
                a1[j] = __builtin_fmaf(q.w, g1, a1[j]);
                if (__any(fabsf(t) < Rk[j])) {
                    float sq = g1 * g1;
                    float p4 = sq * sq;
                    float p8 = p4 * p4;
                    float g2 = p8 * sq;             // g1^10 == exp2(10v)
                    s2[j] = __builtin_fmaf(q.z, g2, s2[j]);
                    a2[j] = __builtin_fmaf(q.w, g2, a2[j]);
                }
            }
        }
    }

    // combine half-waves, publish per-wave partials
    #pragma unroll
    for (int j = 0; j < 4; ++j) {
        s1[j] += __shfl_xor(s1[j], 32);
        a1[j] += __shfl_xor(a1[j], 32);
        s2[j] += __shfl_xor(s2[j], 32);
        a2[j] += __shfl_xor(a2[j], 32);
    }
    if ((tid & 63) < 32) {
        #pragma unroll
        for (int j = 0; j < 4; ++j)
            pbuf[wv][ll + 32 * j] = make_float4(s1[j], a1[j], s2[j], a2[j]);
    }
    __syncthreads();

    // ---- epilogue: thread t finalizes h = t (coalesced stores) ----
    {
        float4 P0 = pbuf[0][tid];
        float4 P1 = pbuf[1][tid];
        float S1 = P0.x + P1.x, A1 = P0.y + P1.y;
        float S2 = P0.z + P1.z, A2 = P0.w + P1.w;
        float a  = fminf(mnbuf[0][tid], mnbuf[1][tid]);
        float mnh = a * a;

        const float LN2 = 0.6931471805599453f;
        float y   = A1 * __builtin_amdgcn_rcpf(S1);
        float wvo = (__builtin_amdgcn_logf(S1) - mnh) * LN2;
        float yt  = A2 * __builtin_amdgcn_rcpf(S2);

        const int o = bc * NH + tid;
        if (is_bf16) {
            __hip_bfloat16* o16 = (__hip_bfloat16*)outp;
            o16[o]           = __float2bfloat16(y);
            o16[BCH + o]     = __float2bfloat16(wvo);
            o16[2 * BCH + o] = __float2bfloat16(yt);
        } else {
            float* o32 = (float*)outp;
            o32[o]           = y;
            o32[BCH + o]     = wvo;
            o32[2 * BCH + o] = yt;
        }
    }
}

extern "C" void kernel_launch(void* const* d_in, const int* in_sizes, int n_in,
                              void* d_out, int out_size, void* d_ws, size_t ws_size,
                              hipStream_t stream) {
    const void* x_t = d_in[0];
    const void* d   = d_in[1];
    const void* m   = d_in[2];
    const void* k   = d_in[3];
    dim3 grid(NB * NC);
    dim3 block(128);
    hipLaunchKernelGGL(sci_kernel, grid, block, 0, stream, x_t, d, m, k, d_out);
}

// Round 7
// 76.162 us; speedup vs baseline: 1.1020x; 1.0733x over previous
//
#include <hip/hip_runtime.h>
#include <hip/hip_bf16.h>

#define NB 32
#define NC 128
#define NW 128
#define NH 128
#define BCH (NB * NC * NH)

// One 128-thread (2-wave) block per (b,c) channel.
// Staging phase: thread = w. Counting-sort the w's by bucket floor(d) (d in
// [0,128)) into LDS; cum[] = exclusive bucket offsets. Compute phase:
// thread = h; iterate ONLY the sorted, contiguous range of w whose d lies in
// [rh-Rh, rh+Rh] -- the only w's with non-negligible weight (~13 of 128).
//
// Exactness: Rh = sqrt(mn0+30)/sA2_min with mn0 = min t'^2 over a non-empty
// probe set. Any w outside the window has t'^2 = A2_w (d-rh)^2 > A2_w Rh^2
// >= mn0+30, so (a) the global argmin is inside the window -> mn computed
// over the window is the EXACT global min (v <= 0, exp2 never overflows,
// kappa peak g2 = 1, no 0/0); (b) dropped e1 terms are each < m*2^-30
// (rel err < 1e-4 << bf16 grain); dropped g2 terms < 2^-300.
// sA2_min is an exact block-wide reduction (no input assumptions).
//
// Math (base 2): sorted entry (sA2, sA2*d, m, m*x), sA2 = sqrt(softplus(k)*log2e)
//   t'  = fma(-sA2, rh, sA2*d);  v = fma(-t', t', mn) <= 0
//   e1  = m * exp2(v);  e2 = m * exp2(10v) = m * g1^10 (4 muls)
//   y = A1/S1;  w_out = (log2(S1) - mn)*ln2;  y_t = A2s/S2
__global__ __launch_bounds__(128, 4) void sci_kernel(
    const void* __restrict__ xp, const void* __restrict__ dp,
    const void* __restrict__ mp, const void* __restrict__ kp,
    void* __restrict__ outp)
{
    const int bc   = blockIdx.x;     // channel
    const int tid  = threadIdx.x;    // staging: w ; compute: h
    const int lane = tid & 63;
    const int wid  = tid >> 6;

    __shared__ float4 tileS[NW];     // sorted (sA2, sA2*d, m, m*x)
    __shared__ float2 tileA[NW];     // sorted (sA2, sA2*d)
    __shared__ int    cum[NW + 1];   // histogram -> exclusive prefix
    __shared__ int    wtot[2];
    __shared__ float  wmin[2];

    // ---- dtype detection (uniform, deterministic) ----
    const unsigned short* du16 = (const unsigned short*)dp;
    bool is_bf16 = true;
    #pragma unroll
    for (int i = 0; i < 32; i += 2) {
        float v = __uint_as_float(((unsigned int)du16[i]) << 16);
        is_bf16 = is_bf16 && (v >= 0.0f) && (v <= 129.0f);
    }

    // ---- load my w ----
    float dv, mv, xv, kv;
    {
        const int base = bc * NW + tid;
        if (is_bf16) {
            dv = __bfloat162float(((const __hip_bfloat16*)dp)[base]);
            mv = __bfloat162float(((const __hip_bfloat16*)mp)[base]);
            xv = __bfloat162float(((const __hip_bfloat16*)xp)[base]);
            kv = __bfloat162float(((const __hip_bfloat16*)kp)[tid]);
        } else {
            dv = ((const float*)dp)[base];
            mv = ((const float*)mp)[base];
            xv = ((const float*)xp)[base];
            kv = ((const float*)kp)[tid];
        }
    }
    const float LOG2E = 1.4426950408889634f;
    float A2  = log1pf(__expf(kv)) * LOG2E;   // softplus(kernel)*log2e
    float sA2 = sqrtf(A2);
    float sd  = sA2 * dv;

    // ---- block-wide min of sA2 ----
    float rmn = sA2;
    #pragma unroll
    for (int o = 32; o >= 1; o >>= 1) rmn = fminf(rmn, __shfl_xor(rmn, o));
    if (lane == 0) wmin[wid] = rmn;

    // ---- counting sort by bucket floor(d) ----
    cum[tid] = 0;
    __syncthreads();                               // wmin + zeroed hist
    int bin  = min(127, max(0, (int)dv));
    int slot = atomicAdd(&cum[bin], 1);
    __syncthreads();                               // all counts in

    int cnt = cum[tid];
    int c = cnt;
    #pragma unroll
    for (int o = 1; o < 64; o <<= 1) {             // inclusive wave scan
        int n = __shfl_up(c, o);
        if (lane >= o) c += n;
    }
    if (lane == 63) wtot[wid] = c;
    __syncthreads();                               // also: all have read cnt
    int excl = c - cnt + (wid ? wtot[0] : 0);
    cum[tid] = excl;                               // overwrite hist -> cum
    if (tid == 0) cum[NW] = NW;
    __syncthreads();

    int pos = cum[bin] + slot;                     // unique slot in [0,128)
    tileS[pos] = make_float4(sA2, sd, mv, mv * xv);
    tileA[pos] = make_float2(sA2, sd);
    __syncthreads();

    const float rsA2min = (1.0f / fminf(wmin[0], wmin[1])) * 1.0005f;

    // ================= compute phase: thread = h =================
    const float rh = (float)tid * (128.0f / 127.0f);

    // phase 1: expand buckets around floor(rh) until non-empty
    int b0 = min(127, (int)rh);
    int s0, e0;
    {
        int r = 0;
        do {
            int lo = max(0, b0 - r);
            int hi = min(127, b0 + r);
            s0 = cum[lo]; e0 = cum[hi + 1];
            ++r;
        } while (s0 == e0);
    }
    float mn0 = 1e30f;
    for (int k = s0; k < e0; ++k) {
        float2 q = tileA[k];
        float t = __builtin_fmaf(-q.x, rh, q.y);
        mn0 = fminf(mn0, t * t);
    }

    // window of relevant w
    float Rh = sqrtf(mn0 + 30.0f) * rsA2min;
    int lo = max(0, (int)(rh - Rh));
    int hi = min(127, (int)(rh + Rh));
    int ks = cum[lo], ke = cum[hi + 1];

    // pass A: exact global min over window
    float mn = 1e30f;
    for (int k = ks; k < ke; ++k) {
        float2 q = tileA[k];
        float t = __builtin_fmaf(-q.x, rh, q.y);
        mn = fminf(mn, t * t);
    }

    // pass B: both softmax sums over window
    float s1 = 0.f, a1 = 0.f, s2 = 0.f, a2 = 0.f;
    for (int k = ks; k < ke; ++k) {
        float4 q = tileS[k];
        float t  = __builtin_fmaf(-q.x, rh, q.y);
        float v  = __builtin_fmaf(-t, t, mn);
        float g1 = __builtin_amdgcn_exp2f(v);
        float sq = g1 * g1;
        float p4 = sq * sq;
        float p8 = p4 * p4;
        float g2 = p8 * sq;                        // g1^10 == exp2(10v)
        s1 = __builtin_fmaf(q.z, g1, s1);
        a1 = __builtin_fmaf(q.w, g1, a1);
        s2 = __builtin_fmaf(q.z, g2, s2);
        a2 = __builtin_fmaf(q.w, g2, a2);
    }

    // epilogue (coalesced: thread = h)
    const float LN2 = 0.6931471805599453f;
    float y  = a1 * __builtin_amdgcn_rcpf(s1);
    float wo = (__builtin_amdgcn_logf(s1) - mn) * LN2;
    float yt = a2 * __builtin_amdgcn_rcpf(s2);

    const int o = bc * NH + tid;
    if (is_bf16) {
        __hip_bfloat16* o16 = (__hip_bfloat16*)outp;
        o16[o]           = __float2bfloat16(y);
        o16[BCH + o]     = __float2bfloat16(wo);
        o16[2 * BCH + o] = __float2bfloat16(yt);
    } else {
        float* o32 = (float*)outp;
        o32[o]           = y;
        o32[BCH + o]     = wo;
        o32[2 * BCH + o] = yt;
    }
}

extern "C" void kernel_launch(void* const* d_in, const int* in_sizes, int n_in,
                              void* d_out, int out_size, void* d_ws, size_t ws_size,
                              hipStream_t stream) {
    const void* x_t = d_in[0];
    const void* d   = d_in[1];
    const void* m   = d_in[2];
    const void* k   = d_in[3];
    dim3 grid(NB * NC);
    dim3 block(128);
    hipLaunchKernelGGL(sci_kernel, grid, block, 0, stream, x_t, d, m, k, d_out);
}

// Round 8
// 73.299 us; speedup vs baseline: 1.1451x; 1.0391x over previous
//
#include <hip/hip_runtime.h>
#include <hip/hip_bf16.h>

#define NB 32
#define NC 128
#define NW 128
#define NH 128
#define BCH (NB * NC * NH)

// One 128-thread (2-wave) block per (b,c) channel.
// Staging: thread = w. Counting-sort w's by bucket floor(d) into LDS (tileS),
// cum[] = exclusive bucket offsets. Compute: thread = h; iterate only the
// sorted contiguous range with d in [rh-Rh, rh+Rh] (~13 of 128 w).
//
// Shift handling (exact, overflow-free): online softmax. Running mn = min
// t'^2 over items processed so far (init = probe min mn0, attained by an
// in-window item). When a new min arrives (rare), rescale s1,a1 by
// f = exp2(t2 - mn) and s2,a2 by f^10. Thus every exp2 argument is <= 0:
// no overflow, kappa peak g2 = 1 (no 0/0), weights identical to the exact
// two-pass version.
//
// Window exactness: Rh = sqrt(mn0+30)/sA2_min, mn0 >= mn_true => any w
// outside the window has t'^2 - mn_true > 30 -> dropped e1 terms each
// < m * 2^-30 (rel err < 1e-4 << bf16 grain); dropped g2 terms < 2^-300.
// The probe-min item lies inside the window (dist = sqrt(mn0/A2_p) < Rh).
//
// Math (base 2): tileS[k] = (sA2, sA2*d, m, m*x), sA2 = sqrt(softplus(k)*log2e)
//   t' = fma(-sA2, rh, sA2*d);  g1 = exp2(mn - t'^2);  g2 = g1^10 (4 muls)
//   y = a1/s1;  w_out = (log2(s1) - mn)*ln2;  y_t = a2/s2
__global__ __launch_bounds__(128, 4) void sci_kernel(
    const void* __restrict__ xp, const void* __restrict__ dp,
    const void* __restrict__ mp, const void* __restrict__ kp,
    void* __restrict__ outp)
{
    const int bc   = blockIdx.x;     // channel
    const int tid  = threadIdx.x;    // staging: w ; compute: h
    const int lane = tid & 63;
    const int wid  = tid >> 6;

    __shared__ float4 tileS[NW];     // sorted (sA2, sA2*d, m, m*x)
    __shared__ int    cum[NW + 1];   // histogram -> exclusive prefix
    __shared__ int    wtot[2];
    __shared__ float  wmin[2];

    // ---- dtype detection (uniform, deterministic) ----
    const unsigned short* du16 = (const unsigned short*)dp;
    bool is_bf16 = true;
    #pragma unroll
    for (int i = 0; i < 32; i += 2) {
        float v = __uint_as_float(((unsigned int)du16[i]) << 16);
        is_bf16 = is_bf16 && (v >= 0.0f) && (v <= 129.0f);
    }

    // ---- load my w ----
    float dv, mv, xv, kv;
    {
        const int base = bc * NW + tid;
        if (is_bf16) {
            dv = __bfloat162float(((const __hip_bfloat16*)dp)[base]);
            mv = __bfloat162float(((const __hip_bfloat16*)mp)[base]);
            xv = __bfloat162float(((const __hip_bfloat16*)xp)[base]);
            kv = __bfloat162float(((const __hip_bfloat16*)kp)[tid]);
        } else {
            dv = ((const float*)dp)[base];
            mv = ((const float*)mp)[base];
            xv = ((const float*)xp)[base];
            kv = ((const float*)kp)[tid];
        }
    }
    const float LOG2E = 1.4426950408889634f;
    float A2  = log1pf(__expf(kv)) * LOG2E;   // softplus(kernel)*log2e
    float sA2 = sqrtf(A2);
    float sd  = sA2 * dv;

    // ---- block-wide min of sA2 ----
    float rmn = sA2;
    #pragma unroll
    for (int o = 32; o >= 1; o >>= 1) rmn = fminf(rmn, __shfl_xor(rmn, o));
    if (lane == 0) wmin[wid] = rmn;

    // ---- counting sort by bucket floor(d) ----
    cum[tid] = 0;
    __syncthreads();                               // wmin + zeroed hist
    int bin  = min(127, max(0, (int)dv));
    int slot = atomicAdd(&cum[bin], 1);
    __syncthreads();                               // all counts in

    int cnt = cum[tid];
    int c = cnt;
    #pragma unroll
    for (int o = 1; o < 64; o <<= 1) {             // inclusive wave scan
        int n = __shfl_up(c, o);
        if (lane >= o) c += n;
    }
    if (lane == 63) wtot[wid] = c;
    __syncthreads();                               // also: all have read cnt
    int excl = c - cnt + (wid ? wtot[0] : 0);
    cum[tid] = excl;                               // overwrite hist -> cum
    if (tid == 0) cum[NW] = NW;
    __syncthreads();

    int pos = cum[bin] + slot;                     // unique slot in [0,128)
    tileS[pos] = make_float4(sA2, sd, mv, mv * xv);
    __syncthreads();

    const float rsA2min = (1.0f / fminf(wmin[0], wmin[1])) * 1.0005f;

    // ================= compute phase: thread = h =================
    const float rh = (float)tid * (128.0f / 127.0f);

    // probe: expand buckets around floor(rh) until non-empty (start r=2)
    int b0 = min(127, (int)rh);
    int s0, e0;
    {
        int r = 2;
        for (;;) {
            int lo = max(0, b0 - r);
            int hi = min(127, b0 + r);
            s0 = cum[lo]; e0 = cum[hi + 1];
            if (s0 != e0) break;
            ++r;
        }
    }
    float mn0 = 1e30f;
    for (int k = s0; k < e0; ++k) {
        float4 q = tileS[k];
        float t = __builtin_fmaf(-q.x, rh, q.y);
        mn0 = fminf(mn0, t * t);
    }

    // window of relevant w
    float Rh = sqrtf(mn0 + 30.0f) * rsA2min;
    int lo = max(0, (int)(rh - Rh));
    int hi = min(127, (int)(rh + Rh));
    int ks = cum[lo], ke = cum[hi + 1];

    // single fused pass: online-softmax over window (unrolled x2)
    float mn = mn0;
    float s1 = 0.f, a1 = 0.f, s2 = 0.f, a2 = 0.f;
    for (int k = ks; k < ke; k += 2) {
        float4 qa = tileS[k];
        int k1 = min(k + 1, NW - 1);
        float4 qb = tileS[k1];
        bool vb = (k + 1 < ke);
        {
            float t  = __builtin_fmaf(-qa.x, rh, qa.y);
            float t2 = t * t;
            if (t2 < mn) {                          // rare: rescale
                float f  = __builtin_amdgcn_exp2f(t2 - mn);
                float fs = f * f, f4 = fs * fs, f8 = f4 * f4;
                float f10 = f8 * fs;
                s1 *= f; a1 *= f; s2 *= f10; a2 *= f10;
                mn = t2;
            }
            float g1 = __builtin_amdgcn_exp2f(mn - t2);
            float sq = g1 * g1, p4 = sq * sq, p8 = p4 * p4;
            float g2 = p8 * sq;                     // g1^10
            s1 = __builtin_fmaf(qa.z, g1, s1);
            a1 = __builtin_fmaf(qa.w, g1, a1);
            s2 = __builtin_fmaf(qa.z, g2, s2);
            a2 = __builtin_fmaf(qa.w, g2, a2);
        }
        if (vb) {
            float t  = __builtin_fmaf(-qb.x, rh, qb.y);
            float t2 = t * t;
            if (t2 < mn) {
                float f  = __builtin_amdgcn_exp2f(t2 - mn);
                float fs = f * f, f4 = fs * fs, f8 = f4 * f4;
                float f10 = f8 * fs;
                s1 *= f; a1 *= f; s2 *= f10; a2 *= f10;
                mn = t2;
            }
            float g1 = __builtin_amdgcn_exp2f(mn - t2);
            float sq = g1 * g1, p4 = sq * sq, p8 = p4 * p4;
            float g2 = p8 * sq;
            s1 = __builtin_fmaf(qb.z, g1, s1);
            a1 = __builtin_fmaf(qb.w, g1, a1);
            s2 = __builtin_fmaf(qb.z, g2, s2);
            a2 = __builtin_fmaf(qb.w, g2, a2);
        }
    }

    // epilogue (coalesced: thread = h)
    const float LN2 = 0.6931471805599453f;
    float y  = a1 * __builtin_amdgcn_rcpf(s1);
    float wo = (__builtin_amdgcn_logf(s1) - mn) * LN2;
    float yt = a2 * __builtin_amdgcn_rcpf(s2);

    const int o = bc * NH + tid;
    if (is_bf16) {
        __hip_bfloat16* o16 = (__hip_bfloat16*)outp;
        o16[o]           = __float2bfloat16(y);
        o16[BCH + o]     = __float2bfloat16(wo);
        o16[2 * BCH + o] = __float2bfloat16(yt);
    } else {
        float* o32 = (float*)outp;
        o32[o]           = y;
        o32[BCH + o]     = wo;
        o32[2 * BCH + o] = yt;
    }
}

extern "C" void kernel_launch(void* const* d_in, const int* in_sizes, int n_in,
                              void* d_out, int out_size, void* d_ws, size_t ws_size,
                              hipStream_t stream) {
    const void* x_t = d_in[0];
    const void* d   = d_in[1];
    const void* m   = d_in[2];
    const void* k   = d_in[3];
    dim3 grid(NB * NC);
    dim3 block(128);
    hipLaunchKernelGGL(sci_kernel, grid, block, 0, stream, x_t, d, m, k, d_out);
}

// Round 9
// 73.286 us; speedup vs baseline: 1.1453x; 1.0002x over previous
//
#include <hip/hip_runtime.h>
#include <hip/hip_bf16.h>

#define NB 32
#define NC 128
#define NW 128
#define NH 128
#define BCH (NB * NC * NH)

// One 128-thread (2-wave) block per (b,c) channel.
// Staging: thread = w. Counting-sort w's by bucket floor(d) into LDS (tileS),
// cum[] = exclusive bucket offsets. Compute: thread = h; iterate only the
// sorted contiguous range with d in [rh-Rh, rh+Rh] (~13 of 128 w).
//
// Hot loop is PAIR-VECTORIZED (float2 components -> v_pk_*_f32 dual-issue):
// items (k,k+1) processed as 2-wide vectors; a short second item is
// neutralized by t2 = 1e30 -> g = exp2(mn-1e30) = 0 exactly (no masked tail
// block). One rescale check per pair via pmin = min(t2a,t2b).
//
// Shift handling (exact, overflow-free): online softmax. Running mn = min
// t'^2 so far (init = probe min mn0). On a new min (rare): rescale s1,a1 by
// f = exp2(pmin - mn), s2,a2 by f^10. Every exp2 arg <= 0: no overflow,
// kappa peak g2 = 1 (no 0/0), weights identical to the exact two-pass form.
//
// Window exactness: Rh = sqrt(mn0+30)/sA2_min, mn0 >= mn_true => any w
// outside has t'^2 - mn_true > 30 -> dropped e1 terms < m*2^-30 each
// (rel err < 1e-4 << bf16 grain); dropped g2 terms < 2^-300.
//
// Math (base 2): tileS[k] = (sA2, sA2*d, m, m*x), sA2 = sqrt(softplus(k)*log2e)
//   t' = fma(-sA2, rh, sA2*d);  g1 = exp2(mn - t'^2);  g2 = g1^10 (pk muls)
//   y = a1/s1;  w_out = (log2(s1) - mn)*ln2;  y_t = a2/s2
__global__ __launch_bounds__(128, 4) void sci_kernel(
    const void* __restrict__ xp, const void* __restrict__ dp,
    const void* __restrict__ mp, const void* __restrict__ kp,
    void* __restrict__ outp)
{
    const int bc   = blockIdx.x;     // channel
    const int tid  = threadIdx.x;    // staging: w ; compute: h
    const int lane = tid & 63;
    const int wid  = tid >> 6;

    __shared__ float4 tileS[NW];     // sorted (sA2, sA2*d, m, m*x)
    __shared__ int    cum[NW + 1];   // histogram -> exclusive prefix
    __shared__ int    wtot[2];
    __shared__ float  wmin[2];

    // ---- dtype detection (uniform, deterministic) ----
    const unsigned short* du16 = (const unsigned short*)dp;
    bool is_bf16 = true;
    #pragma unroll
    for (int i = 0; i < 32; i += 2) {
        float v = __uint_as_float(((unsigned int)du16[i]) << 16);
        is_bf16 = is_bf16 && (v >= 0.0f) && (v <= 129.0f);
    }

    // ---- load my w ----
    float dv, mv, xv, kv;
    {
        const int base = bc * NW + tid;
        if (is_bf16) {
            dv = __bfloat162float(((const __hip_bfloat16*)dp)[base]);
            mv = __bfloat162float(((const __hip_bfloat16*)mp)[base]);
            xv = __bfloat162float(((const __hip_bfloat16*)xp)[base]);
            kv = __bfloat162float(((const __hip_bfloat16*)kp)[tid]);
        } else {
            dv = ((const float*)dp)[base];
            mv = ((const float*)mp)[base];
            xv = ((const float*)xp)[base];
            kv = ((const float*)kp)[tid];
        }
    }
    const float LOG2E = 1.4426950408889634f;
    float A2  = log1pf(__expf(kv)) * LOG2E;   // softplus(kernel)*log2e
    float sA2 = sqrtf(A2);
    float sd  = sA2 * dv;

    // ---- block-wide min of sA2 ----
    float rmn = sA2;
    #pragma unroll
    for (int o = 32; o >= 1; o >>= 1) rmn = fminf(rmn, __shfl_xor(rmn, o));
    if (lane == 0) wmin[wid] = rmn;

    // ---- counting sort by bucket floor(d) ----
    cum[tid] = 0;
    __syncthreads();                               // wmin + zeroed hist
    int bin  = min(127, max(0, (int)dv));
    int slot = atomicAdd(&cum[bin], 1);
    __syncthreads();                               // all counts in

    int cnt = cum[tid];
    int c = cnt;
    #pragma unroll
    for (int o = 1; o < 64; o <<= 1) {             // inclusive wave scan
        int n = __shfl_up(c, o);
        if (lane >= o) c += n;
    }
    if (lane == 63) wtot[wid] = c;
    __syncthreads();                               // also: all have read cnt
    int excl = c - cnt + (wid ? wtot[0] : 0);
    cum[tid] = excl;                               // overwrite hist -> cum
    if (tid == 0) cum[NW] = NW;
    __syncthreads();

    int pos = cum[bin] + slot;                     // unique slot in [0,128)
    tileS[pos] = make_float4(sA2, sd, mv, mv * xv);
    __syncthreads();

    const float rsA2min = (1.0f / fminf(wmin[0], wmin[1])) * 1.0005f;

    // ================= compute phase: thread = h =================
    const float rh = (float)tid * (128.0f / 127.0f);

    // probe: expand buckets around floor(rh) until non-empty (start r=2)
    int b0 = min(127, (int)rh);
    int s0, e0;
    {
        int r = 2;
        for (;;) {
            int lo = max(0, b0 - r);
            int hi = min(127, b0 + r);
            s0 = cum[lo]; e0 = cum[hi + 1];
            if (s0 != e0) break;
            ++r;
        }
    }
    float mn0 = 1e30f;
    for (int k = s0; k < e0; ++k) {
        float4 q = tileS[k];
        float t = __builtin_fmaf(-q.x, rh, q.y);
        mn0 = fminf(mn0, t * t);
    }

    // window of relevant w
    float Rh = sqrtf(mn0 + 30.0f) * rsA2min;
    int lo = max(0, (int)(rh - Rh));
    int hi = min(127, (int)(rh + Rh));
    int ks = cum[lo], ke = cum[hi + 1];

    // fused online-softmax pass, pair-vectorized (v_pk_*_f32 friendly)
    float mn = mn0;
    float s1x = 0.f, s1y = 0.f, a1x = 0.f, a1y = 0.f;
    float s2x = 0.f, s2y = 0.f, a2x = 0.f, a2y = 0.f;
    for (int k = ks; k < ke; k += 2) {
        float4 qa = tileS[k];
        float4 qb = tileS[min(k + 1, NW - 1)];
        float tx = __builtin_fmaf(-qa.x, rh, qa.y);
        float ty = __builtin_fmaf(-qb.x, rh, qb.y);
        float t2x = tx * tx;
        float t2y = (k + 1 < ke) ? ty * ty : 1e30f;  // dead item -> g = 0
        float pmin = fminf(t2x, t2y);
        if (pmin < mn) {                             // rare: rescale both
            float f  = __builtin_amdgcn_exp2f(pmin - mn);
            float fs = f * f, f4 = fs * fs, f8 = f4 * f4;
            float f10 = f8 * fs;
            s1x *= f;   s1y *= f;   a1x *= f;   a1y *= f;
            s2x *= f10; s2y *= f10; a2x *= f10; a2y *= f10;
            mn = pmin;
        }
        float g1x = __builtin_amdgcn_exp2f(mn - t2x);
        float g1y = __builtin_amdgcn_exp2f(mn - t2y);
        float sqx = g1x * g1x, sqy = g1y * g1y;
        float p4x = sqx * sqx, p4y = sqy * sqy;
        float p8x = p4x * p4x, p8y = p4y * p4y;
        float g2x = p8x * sqx, g2y = p8y * sqy;      // g1^10
        s1x = __builtin_fmaf(qa.z, g1x, s1x);  s1y = __builtin_fmaf(qb.z, g1y, s1y);
        a1x = __builtin_fmaf(qa.w, g1x, a1x);  a1y = __builtin_fmaf(qb.w, g1y, a1y);
        s2x = __builtin_fmaf(qa.z, g2x, s2x);  s2y = __builtin_fmaf(qb.z, g2y, s2y);
        a2x = __builtin_fmaf(qa.w, g2x, a2x);  a2y = __builtin_fmaf(qb.w, g2y, a2y);
    }
    float s1 = s1x + s1y, a1 = a1x + a1y;
    float s2 = s2x + s2y, a2 = a2x + a2y;

    // epilogue (coalesced: thread = h)
    const float LN2 = 0.6931471805599453f;
    float y  = a1 * __builtin_amdgcn_rcpf(s1);
    float wo = (__builtin_amdgcn_logf(s1) - mn) * LN2;
    float yt = a2 * __builtin_amdgcn_rcpf(s2);

    const int o = bc * NH + tid;
    if (is_bf16) {
        __hip_bfloat16* o16 = (__hip_bfloat16*)outp;
        o16[o]           = __float2bfloat16(y);
        o16[BCH + o]     = __float2bfloat16(wo);
        o16[2 * BCH + o] = __float2bfloat16(yt);
    } else {
        float* o32 = (float*)outp;
        o32[o]           = y;
        o32[BCH + o]     = wo;
        o32[2 * BCH + o] = yt;
    }
}

extern "C" void kernel_launch(void* const* d_in, const int* in_sizes, int n_in,
                              void* d_out, int out_size, void* d_ws, size_t ws_size,
                              hipStream_t stream) {
    const void* x_t = d_in[0];
    const void* d   = d_in[1];
    const void* m   = d_in[2];
    const void* k   = d_in[3];
    dim3 grid(NB * NC);
    dim3 block(128);
    hipLaunchKernelGGL(sci_kernel, grid, block, 0, stream, x_t, d, m, k, d_out);
}

// Round 10
// 73.106 us; speedup vs baseline: 1.1481x; 1.0025x over previous
//
#include <hip/hip_runtime.h>
#include <hip/hip_bf16.h>

#define NB 32
#define NC 128
#define NW 128
#define NH 128
#define BCH (NB * NC * NH)

// One 128-thread (2-wave) block per (b,c) channel.
// Staging: thread = w. Counting-sort w's by bucket floor(d) into LDS (tileS),
// cum[] = exclusive bucket offsets. Compute: thread = h; online-softmax over
// ONLY the sorted contiguous range with d in [rh-Rh, rh+Rh].
//
// Cutoff: Rh = sqrt(mn_c + 12)/sA2_min (g1 cutoff 2^-12; bf16 threshold has
// 65x headroom at the previous 2^-30 cutoff). Argmin stays in-window: any
// outside item has t'^2 > mn_c + 12 >= mn_true. Dropped e1 terms each
// < m*2^-12 of the peak; dropped kappa terms < 2^-120.
//
// Probe ring (r=2 around floor(rh), expanded if empty) is FUSED into the
// accumulation via online softmax (running mn; on new min rescale s1,a1 by
// f=exp2(old-new gap), s2,a2 by f^10). The window pass then covers only the
// residual ranges [ks,s0) and [e0,ke). Every exp2 arg <= 0: no overflow,
// kappa peak g2 = 1 (no 0/0).
//
// Math (base 2): tileS[k] = (sA2, sA2*d, m, m*x), sA2 = sqrt(softplus(k)*log2e)
//   t' = fma(-sA2, rh, sA2*d);  g1 = exp2(mn - t'^2);  g2 = g1^10 (4 muls)
//   y = a1/s1;  w_out = (log2(s1) - mn)*ln2;  y_t = a2/s2
__global__ __launch_bounds__(128, 4) void sci_kernel(
    const void* __restrict__ xp, const void* __restrict__ dp,
    const void* __restrict__ mp, const void* __restrict__ kp,
    void* __restrict__ outp)
{
    const int bc   = blockIdx.x;     // channel
    const int tid  = threadIdx.x;    // staging: w ; compute: h
    const int lane = tid & 63;
    const int wid  = tid >> 6;

    __shared__ float4 tileS[NW];     // sorted (sA2, sA2*d, m, m*x)
    __shared__ int    cum[NW + 1];   // histogram -> exclusive prefix
    __shared__ int    wtot[2];
    __shared__ float  wmin[2];

    // ---- dtype detection (uniform, deterministic) ----
    const unsigned short* du16 = (const unsigned short*)dp;
    bool is_bf16 = true;
    #pragma unroll
    for (int i = 0; i < 32; i += 2) {
        float v = __uint_as_float(((unsigned int)du16[i]) << 16);
        is_bf16 = is_bf16 && (v >= 0.0f) && (v <= 129.0f);
    }

    // ---- load my w ----
    float dv, mv, xv, kv;
    {
        const int base = bc * NW + tid;
        if (is_bf16) {
            dv = __bfloat162float(((const __hip_bfloat16*)dp)[base]);
            mv = __bfloat162float(((const __hip_bfloat16*)mp)[base]);
            xv = __bfloat162float(((const __hip_bfloat16*)xp)[base]);
            kv = __bfloat162float(((const __hip_bfloat16*)kp)[tid]);
        } else {
            dv = ((const float*)dp)[base];
            mv = ((const float*)mp)[base];
            xv = ((const float*)xp)[base];
            kv = ((const float*)kp)[tid];
        }
    }
    const float LOG2E = 1.4426950408889634f;
    // softplus(k)*log2e = log2(1 + 2^(k*log2e))  -- 2 HW trans ops, no libm
    float ex  = __builtin_amdgcn_exp2f(kv * LOG2E);
    float A2  = __builtin_amdgcn_logf(1.0f + ex);
    float sA2 = sqrtf(A2);
    float sd  = sA2 * dv;

    // ---- block-wide min of sA2 ----
    float rmn = sA2;
    #pragma unroll
    for (int o = 32; o >= 1; o >>= 1) rmn = fminf(rmn, __shfl_xor(rmn, o));
    if (lane == 0) wmin[wid] = rmn;

    // ---- counting sort by bucket floor(d) ----
    cum[tid] = 0;
    __syncthreads();                               // wmin + zeroed hist
    int bin  = min(127, max(0, (int)dv));
    int slot = atomicAdd(&cum[bin], 1);
    __syncthreads();                               // all counts in

    int cnt = cum[tid];
    int c = cnt;
    #pragma unroll
    for (int o = 1; o < 64; o <<= 1) {             // inclusive wave scan
        int n = __shfl_up(c, o);
        if (lane >= o) c += n;
    }
    if (lane == 63) wtot[wid] = c;
    __syncthreads();                               // also: all have read cnt
    int excl = c - cnt + (wid ? wtot[0] : 0);
    cum[tid] = excl;                               // overwrite hist -> cum
    if (tid == 0) cum[NW] = NW;
    __syncthreads();

    int pos = cum[bin] + slot;                     // unique slot in [0,128)
    tileS[pos] = make_float4(sA2, sd, mv, mv * xv);
    __syncthreads();

    const float rsA2min = (1.0f / fminf(wmin[0], wmin[1])) * 1.0005f;

    // ================= compute phase: thread = h =================
    const float rh = (float)tid * (128.0f / 127.0f);

    float mn = 1e30f;
    float s1 = 0.f, a1 = 0.f, s2 = 0.f, a2 = 0.f;

    auto body = [&](int k) {
        float4 q = tileS[k];
        float t  = __builtin_fmaf(-q.x, rh, q.y);
        float t2 = t * t;
        if (t2 < mn) {                              // rare: rescale
            float f  = __builtin_amdgcn_exp2f(t2 - mn);  // first hit: f=0
            float fs = f * f, f4 = fs * fs, f8 = f4 * f4;
            float f10 = f8 * fs;
            s1 *= f; a1 *= f; s2 *= f10; a2 *= f10;
            mn = t2;
        }
        float g1 = __builtin_amdgcn_exp2f(mn - t2);
        float sq = g1 * g1, p4 = sq * sq, p8 = p4 * p4;
        float g2 = p8 * sq;                         // g1^10
        s1 = __builtin_fmaf(q.z, g1, s1);
        a1 = __builtin_fmaf(q.w, g1, a1);
        s2 = __builtin_fmaf(q.z, g2, s2);
        a2 = __builtin_fmaf(q.w, g2, a2);
    };

    // probe ring around floor(rh), expanded until non-empty; FUSED accumulate
    int b0 = min(127, (int)rh);
    int lo0, hi0, s0, e0;
    {
        int r = 2;
        for (;;) {
            lo0 = max(0, b0 - r); hi0 = min(127, b0 + r);
            s0 = cum[lo0]; e0 = cum[hi0 + 1];
            if (s0 != e0) break;
            ++r;
        }
    }
    for (int k = s0; k < e0; ++k) body(k);          // mn now = center min

    // residual window (cutoff 2^-12)
    float Rh = sqrtf(mn + 12.0f) * rsA2min;
    int lo = min(lo0, max(0, (int)(rh - Rh)));
    int hi = max(hi0, min(127, (int)(rh + Rh)));
    int ks = cum[lo], ke = cum[hi + 1];
    for (int k = ks; k < s0; ++k) body(k);
    for (int k = e0; k < ke; ++k) body(k);

    // epilogue (coalesced: thread = h)
    const float LN2 = 0.6931471805599453f;
    float y  = a1 * __builtin_amdgcn_rcpf(s1);
    float wo = (__builtin_amdgcn_logf(s1) - mn) * LN2;
    float yt = a2 * __builtin_amdgcn_rcpf(s2);

    const int o = bc * NH + tid;
    if (is_bf16) {
        __hip_bfloat16* o16 = (__hip_bfloat16*)outp;
        o16[o]           = __float2bfloat16(y);
        o16[BCH + o]     = __float2bfloat16(wo);
        o16[2 * BCH + o] = __float2bfloat16(yt);
    } else {
        float* o32 = (float*)outp;
        o32[o]           = y;
        o32[BCH + o]     = wo;
        o32[2 * BCH + o] = yt;
    }
}

extern "C" void kernel_launch(void* const* d_in, const int* in_sizes, int n_in,
                              void* d_out, int out_size, void* d_ws, size_t ws_size,
                              hipStream_t stream) {
    const void* x_t = d_in[0];
    const void* d   = d_in[1];
    const void* m   = d_in[2];
    const void* k   = d_in[3];
    dim3 grid(NB * NC);
    dim3 block(128);
    hipLaunchKernelGGL(sci_kernel, grid, block, 0, stream, x_t, d, m, k, d_out);
}

// Round 12
// 72.657 us; speedup vs baseline: 1.1552x; 1.0062x over previous
//
#include <hip/hip_runtime.h>
#include <hip/hip_bf16.h>

#define NB 32
#define NC 128
#define NW 128
#define NH 128
#define BCH (NB * NC * NH)

// One 128-thread (2-wave) block per (b,c) channel.
// Staging: thread = w. Counting-sort w's by bucket floor(d) into LDS (tileS),
// cum[] = exclusive bucket offsets. Compute: thread = h; online-softmax over
// ONLY the sorted contiguous range with d in [rh-Rh, rh+Rh].
//
// Cutoff: Rh = sqrt(mn_c + 12)/sA2_min (g1 cutoff 2^-12; bf16 threshold has
// ~30x headroom at this cutoff). Argmin stays in-window: any outside item
// has t'^2 > mn_c + 12 >= mn_true. Dropped e1 terms each < m*2^-12 of the
// peak; dropped kappa terms < 2^-120.
//
// Probe ring (r=2 around floor(rh), expanded if empty) is FUSED into the
// accumulation via online softmax (running mn; on new min rescale s1,a1 by
// f=exp2(old-new gap), s2,a2 by f^10). The window pass then covers only the
// residual ranges [ks,s0) and [e0,ke). Every exp2 arg <= 0: no overflow,
// kappa peak g2 = 1 (no 0/0).
//
// Math (base 2): tileS[k] = (sA2, sA2*d, m, m*x), sA2 = sqrt(softplus(k)*log2e)
//   t' = fma(-sA2, rh, sA2*d);  g1 = exp2(mn - t'^2);  g2 = g1^10 (4 muls)
//   y = a1/s1;  w_out = (log2(s1) - mn)*ln2;  y_t = a2/s2
__global__ __launch_bounds__(128, 4) void sci_kernel(
    const void* __restrict__ xp, const void* __restrict__ dp,
    const void* __restrict__ mp, const void* __restrict__ kp,
    void* __restrict__ outp)
{
    const int bc   = blockIdx.x;     // channel
    const int tid  = threadIdx.x;    // staging: w ; compute: h
    const int lane = tid & 63;
    const int wid  = tid >> 6;

    __shared__ float4 tileS[NW];     // sorted (sA2, sA2*d, m, m*x)
    __shared__ int    cum[NW + 1];   // histogram -> exclusive prefix
    __shared__ int    wtot[2];
    __shared__ float  wmin[2];

    // ---- dtype detection (uniform, deterministic) ----
    const unsigned short* du16 = (const unsigned short*)dp;
    bool is_bf16 = true;
    #pragma unroll
    for (int i = 0; i < 32; i += 2) {
        float v = __uint_as_float(((unsigned int)du16[i]) << 16);
        is_bf16 = is_bf16 && (v >= 0.0f) && (v <= 129.0f);
    }

    // ---- load my w ----
    float dv, mv, xv, kv;
    {
        const int base = bc * NW + tid;
        if (is_bf16) {
            dv = __bfloat162float(((const __hip_bfloat16*)dp)[base]);
            mv = __bfloat162float(((const __hip_bfloat16*)mp)[base]);
            xv = __bfloat162float(((const __hip_bfloat16*)xp)[base]);
            kv = __bfloat162float(((const __hip_bfloat16*)kp)[tid]);
        } else {
            dv = ((const float*)dp)[base];
            mv = ((const float*)mp)[base];
            xv = ((const float*)xp)[base];
            kv = ((const float*)kp)[tid];
        }
    }
    const float LOG2E = 1.4426950408889634f;
    // softplus(k)*log2e = log2(1 + 2^(k*log2e))  -- 2 HW trans ops, no libm
    float ex  = __builtin_amdgcn_exp2f(kv * LOG2E);
    float A2  = __builtin_amdgcn_logf(1.0f + ex);
    float sA2 = sqrtf(A2);
    float sd  = sA2 * dv;

    // ---- block-wide min of sA2 ----
    float rmn = sA2;
    #pragma unroll
    for (int o = 32; o >= 1; o >>= 1) rmn = fminf(rmn, __shfl_xor(rmn, o));
    if (lane == 0) wmin[wid] = rmn;

    // ---- counting sort by bucket floor(d) ----
    cum[tid] = 0;
    __syncthreads();                               // wmin + zeroed hist
    int bin  = min(127, max(0, (int)dv));
    int slot = atomicAdd(&cum[bin], 1);
    __syncthreads();                               // all counts in

    int cnt = cum[tid];
    int c = cnt;
    #pragma unroll
    for (int o = 1; o < 64; o <<= 1) {             // inclusive wave scan
        int n = __shfl_up(c, o);
        if (lane >= o) c += n;
    }
    if (lane == 63) wtot[wid] = c;
    __syncthreads();                               // also: all have read cnt
    int excl = c - cnt + (wid ? wtot[0] : 0);
    cum[tid] = excl;                               // overwrite hist -> cum
    if (tid == 0) cum[NW] = NW;
    __syncthreads();

    int pos = cum[bin] + slot;                     // unique slot in [0,128)
    tileS[pos] = make_float4(sA2, sd, mv, mv * xv);
    __syncthreads();

    const float rsA2min = (1.0f / fminf(wmin[0], wmin[1])) * 1.0005f;

    // ================= compute phase: thread = h =================
    const float rh = (float)tid * (128.0f / 127.0f);

    float mn = 1e30f;
    float s1 = 0.f, a1 = 0.f, s2 = 0.f, a2 = 0.f;

    auto body = [&](int k) {
        float4 q = tileS[k];
        float t  = __builtin_fmaf(-q.x, rh, q.y);
        float t2 = t * t;
        if (t2 < mn) {                              // rare: rescale
            float f  = __builtin_amdgcn_exp2f(t2 - mn);  // first hit: f=0
            float fs = f * f, f4 = fs * fs, f8 = f4 * f4;
            float f10 = f8 * fs;
            s1 *= f; a1 *= f; s2 *= f10; a2 *= f10;
            mn = t2;
        }
        float g1 = __builtin_amdgcn_exp2f(mn - t2);
        float sq = g1 * g1, p4 = sq * sq, p8 = p4 * p4;
        float g2 = p8 * sq;                         // g1^10
        s1 = __builtin_fmaf(q.z, g1, s1);
        a1 = __builtin_fmaf(q.w, g1, a1);
        s2 = __builtin_fmaf(q.z, g2, s2);
        a2 = __builtin_fmaf(q.w, g2, a2);
    };

    // probe ring around floor(rh), expanded until non-empty; FUSED accumulate
    int b0 = min(127, (int)rh);
    int lo0, hi0, s0, e0;
    {
        int r = 2;
        for (;;) {
            lo0 = max(0, b0 - r); hi0 = min(127, b0 + r);
            s0 = cum[lo0]; e0 = cum[hi0 + 1];
            if (s0 != e0) break;
            ++r;
        }
    }
    for (int k = s0; k < e0; ++k) body(k);          // mn now = center min

    // residual window (cutoff 2^-12)
    float Rh = sqrtf(mn + 12.0f) * rsA2min;
    int lo = min(lo0, max(0, (int)(rh - Rh)));
    int hi = max(hi0, min(127, (int)(rh + Rh)));
    int ks = cum[lo], ke = cum[hi + 1];
    for (int k = ks; k < s0; ++k) body(k);
    for (int k = e0; k < ke; ++k) body(k);

    // epilogue (coalesced: thread = h)
    const float LN2 = 0.6931471805599453f;
    float y  = a1 * __builtin_amdgcn_rcpf(s1);
    float wo = (__builtin_amdgcn_logf(s1) - mn) * LN2;
    float yt = a2 * __builtin_amdgcn_rcpf(s2);

    const int o = bc * NH + tid;
    if (is_bf16) {
        __hip_bfloat16* o16 = (__hip_bfloat16*)outp;
        o16[o]           = __float2bfloat16(y);
        o16[BCH + o]     = __float2bfloat16(wo);
        o16[2 * BCH + o] = __float2bfloat16(yt);
    } else {
        float* o32 = (float*)outp;
        o32[o]           = y;
        o32[BCH + o]     = wo;
        o32[2 * BCH + o] = yt;
    }
}

extern "C" void kernel_launch(void* const* d_in, const int* in_sizes, int n_in,
                              void* d_out, int out_size, void* d_ws, size_t ws_size,
                              hipStream_t stream) {
    const void* x_t = d_in[0];
    const void* d   = d_in[1];
    const void* m   = d_in[2];
    const void* k   = d_in[3];
    dim3 grid(NB * NC);
    dim3 block(128);
    hipLaunchKernelGGL(sci_kernel, grid, block, 0, stream, x_t, d, m, k, d_out);
}